// Round 9
// baseline (341.966 us; speedup 1.0000x reference)
//
#include <hip/hip_runtime.h>
#include <hip/hip_cooperative_groups.h>
#include <stdint.h>

namespace cg = cooperative_groups;

typedef uint16_t u16;
typedef uint32_t u32;
typedef uint64_t u64;

#define CONF_THRESH 0.5f
#define PIOU_THRESH 0.5f
#define ECAP 128   // external-suppressor slots per column (total suppressors <=128, verified R7/R8)
#define TMAX 64    // max Gauss-Seidel sweeps; early-exit certifies fixpoint

// ---------------------------------------------------------------------------
// K1a: conf rank (desc, tie rank asc) via O(N^2) counting.
// ---------------------------------------------------------------------------
__global__ void rank_kernel(const float* __restrict__ in, u32* __restrict__ rank, int N) {
    __shared__ u64 keys[2048];
    int t = threadIdx.x;
    int i = blockIdx.x * 256 + t;
    int j0 = blockIdx.y * 2048;
    for (int k = t; k < 2048; k += 256) {
        int j = j0 + k;
        u64 key = 0;
        if (j < N) {
            u32 cb = __float_as_uint(in[(size_t)j * 5]);
            key = ((u64)cb << 32) | (u64)(0xFFFFFFFFu - (u32)j);
        }
        keys[k] = key;
    }
    __syncthreads();
    if (i >= N) return;
    u32 cbi = __float_as_uint(in[(size_t)i * 5]);
    u64 mykey = ((u64)cbi << 32) | (u64)(0xFFFFFFFFu - (u32)i);
    int cnt = 0;
    for (int k = 0; k < 2048; ++k) cnt += (keys[k] > mykey) ? 1 : 0;
    if (cnt) atomicAdd(&rank[i], (u32)cnt);
}

// ---------------------------------------------------------------------------
// K1b: scatter boxes into rank order + count valid M (valid = prefix).
// ---------------------------------------------------------------------------
__global__ void scatter_kernel(const float* __restrict__ in, const u32* __restrict__ rank,
                               float4* __restrict__ sbox, u32* __restrict__ Mctr, int N) {
    int i = blockIdx.x * 256 + threadIdx.x;
    if (i >= N) return;
    float c = in[(size_t)i * 5 + 0];
    float s = in[(size_t)i * 5 + 1];
    float e = in[(size_t)i * 5 + 2];
    float p = in[(size_t)i * 5 + 3];
    float h = in[(size_t)i * 5 + 4];
    u32 r = rank[i];
    sbox[r] = make_float4(s, e, p, h);
    if (c > CONF_THRESH) atomicAdd(Mctr, 1u);
}

// ---------------------------------------------------------------------------
// K1c: spatial rank among valid ranks r<M: spos[r] = #{r'<M : key(r')<key(r)},
// key = start_bits<<32 | r (start>=0 so float bits order-preserving).
// ---------------------------------------------------------------------------
__global__ void spos_kernel(const float4* __restrict__ sbox, const u32* __restrict__ Mptr,
                            u32* __restrict__ spos, int N) {
    __shared__ u64 keys[2048];
    int M = (int)*Mptr;
    int t = threadIdx.x;
    int i = blockIdx.x * 256 + t;
    int j0 = blockIdx.y * 2048;
    for (int k = t; k < 2048; k += 256) {
        int j = j0 + k;
        u64 key = ~0ull;   // +inf: never counted as less
        if (j < M) key = ((u64)__float_as_uint(sbox[j].x) << 32) | (u32)j;
        keys[k] = key;
    }
    __syncthreads();
    if (i >= M) return;
    u64 mykey = ((u64)__float_as_uint(sbox[i].x) << 32) | (u32)i;
    int cnt = 0;
    for (int k = 0; k < 2048; ++k) cnt += (keys[k] < mykey) ? 1 : 0;
    if (cnt) atomicAdd(&spos[i], (u32)cnt);
}

// ---------------------------------------------------------------------------
// K1d: within-chunk rank: li[r] = #{r'<r, valid, spos'>>8 == spos>>8}.
// ---------------------------------------------------------------------------
__global__ void li_kernel(const u32* __restrict__ spos, const u32* __restrict__ Mptr,
                          u32* __restrict__ li, int N) {
    __shared__ u32 sp[2048];
    int M = (int)*Mptr;
    int t = threadIdx.x;
    int i = blockIdx.x * 256 + t;
    int j0 = blockIdx.y * 2048;
    for (int k = t; k < 2048; k += 256) {
        int j = j0 + k;
        sp[k] = (j < M) ? spos[j] : 0xFFFFFFFFu;
    }
    __syncthreads();
    if (i >= M) return;
    u32 mych = spos[i] >> 8;
    int cnt = 0;
    for (int k = 0; k < 2048; ++k)
        cnt += ((j0 + k < i) && ((sp[k] >> 8) == mych)) ? 1 : 0;
    if (cnt) atomicAdd(&li[i], (u32)cnt);
}

// K1e: gidx[r] = chunk*256 + within-chunk-rank  (bijection valid ranks -> [0,M))
__global__ void gidx_kernel(const u32* __restrict__ spos, const u32* __restrict__ li,
                            const u32* __restrict__ Mptr, u16* __restrict__ gidx, int N) {
    int r = blockIdx.x * 256 + threadIdx.x;
    int M = (int)*Mptr;
    if (r >= M) return;
    gidx[r] = (u16)((spos[r] >> 8) * 256 + li[r]);
}

// ---------------------------------------------------------------------------
// K2: suppression edges in gidx space. One wave per rank-column j<M.
// Same-chunk edge -> bit in intraT[chunk] (t32 layout [s][v][lane][half]);
// cross-chunk edge -> append suppressor gidx to ext[gj], count in ext_cnt.
// ---------------------------------------------------------------------------
__global__ void mask_spatial_kernel(const float4* __restrict__ sbox, const u32* __restrict__ Mptr,
                                    const u16* __restrict__ gidx, u32* __restrict__ intraT,
                                    u16* __restrict__ ext, u16* __restrict__ ext_cnt, int N) {
#pragma clang fp contract(off)
    int M = (int)*Mptr;
    int wave = threadIdx.x >> 6, lane = threadIdx.x & 63;
    int j = blockIdx.x * 4 + wave;
    if (j >= M) return;
    float4 bj = sbox[j];
    float areaj = (bj.y - bj.x) * bj.w;
    int gj = (int)gidx[j];
    int chj = gj >> 8, lj = gj & 255;
    u32* tchunk = intraT + (size_t)chj * 2048;
    int wend = j >> 6;
    int cnt = 0;
    for (int w = 0; w <= wend; ++w) {
        int i = w * 64 + lane;
        float4 bi = sbox[i];
        float inter_start = fmaxf(bi.x, bj.x);
        float inter_end   = fminf(bi.y, bj.y);
        float inter_len   = fmaxf(inter_end - inter_start, 0.0f);
        float inter_h     = fminf(bi.w, bj.w);
        float inter_area  = inter_len * inter_h;
        float areai       = (bi.y - bi.x) * bi.w;
        float union_area  = areai + areaj - inter_area;
        float iou         = inter_area / union_area;
        float peak_dist   = fabsf(bi.z - bj.z);
        float union_start = fminf(bi.x, bj.x);
        float union_end   = fmaxf(bi.y, bj.y);
        float union_dist  = fabsf(union_end - union_start);
        float piou        = iou - peak_dist / union_dist;
        bool hit = (i < j) && (piou > PIOU_THRESH);
        int gi = 0;
        if (hit) gi = (int)gidx[i];
        bool intra = hit && ((gi >> 8) == chj);
        bool exth  = hit && !intra;
        if (intra) {
            int ri = gi & 255;
            atomicOr(&tchunk[(((ri >> 6) * 4 + (lj >> 6)) * 64 + (lj & 63)) * 2 + ((ri >> 5) & 1)],
                     1u << (ri & 31));
        }
        u64 be = __ballot(exth);
        if (exth) {
            int slot = cnt + (int)__builtin_popcountll(be & ((1ull << lane) - 1ull));
            if (slot < ECAP) ext[(size_t)gj * ECAP + slot] = (u16)gi;
        }
        cnt += (int)__builtin_popcountll(be);
    }
    if (lane == 0) ext_cnt[gj] = (u16)min(cnt, ECAP);
}

// ---------------------------------------------------------------------------
// K3: spatial-chunk Gauss-Seidel fixpoint (cooperative, 64 blocks x 256).
// Block b owns gidx chunk [256b, 256b+256): per sweep it solves its chunk
// EXACTLY (ballot-ctz greedy over the LDS intra matrix, rank order) given
// externals from keepA. Unique fixpoint = exact greedy; no-change certifies.
// Sweeps ~= 1 + max chunk-boundary crossings of any suppression chain.
// ---------------------------------------------------------------------------
#define EXT_TEST(VAL, IDX) \
    if ((IDX) < ec) { int q = (int)(VAL); rm |= (kA[q >> 5] >> (q & 31)) & 1u; }

__global__ void __launch_bounds__(256) nms_gs_kernel(
        const u32* __restrict__ intraT, const u16* __restrict__ ext,
        const u16* __restrict__ ext_cnt, const u32* __restrict__ Mptr,
        u32* keepA, u32* keepB, u32* __restrict__ changed, u32* __restrict__ keepf) {
    cg::grid_group grid = cg::this_grid();
    int b = (int)blockIdx.x, tid = threadIdx.x, wave = tid >> 6, lane = tid & 63;
    int M = (int)*Mptr;
    int Cnum = (M + 255) >> 8;
    bool activeb = (b < Cnum);

    __shared__ u32 t32[2048];   // 8 KB intra matrix
    __shared__ u32 kA[512];     // staged keep bitset (gidx space)
    __shared__ u32 rmw[8];      // external-removed bits for 256 local cols

    if (activeb)
        for (int q = tid; q < 2048; q += 256) t32[q] = intraT[(size_t)b * 2048 + q];

    // init BOTH buffers for my 8 words: bit set iff gidx < M (keep = valid)
    if (tid < 8) {
        int wi = b * 8 + tid, lo = wi * 32;
        u32 v = (M >= lo + 32) ? 0xFFFFFFFFu : ((M <= lo) ? 0u : ((1u << (M - lo)) - 1u));
        keepA[wi] = v; keepB[wi] = v;
    }

    int g = b * 256 + tid;
    bool validc = activeb && (g < M);
    int ec = validc ? (int)ext_cnt[g] : 0;
    uint4 c0 = make_uint4(0, 0, 0, 0), c1 = make_uint4(0, 0, 0, 0);
    const uint4* ep = (const uint4*)(ext + (size_t)g * ECAP);
    if (ec > 0) c0 = ep[0];
    if (ec > 8) c1 = ep[1];

    __threadfence();
    grid.sync();

    u32* A = keepA; u32* B = keepB;
    for (int t = 0; t < TMAX; ++t) {
        for (int q = tid; q < 512; q += 256)
            kA[q] = __hip_atomic_load(&A[q], __ATOMIC_RELAXED, __HIP_MEMORY_SCOPE_AGENT);
        __syncthreads();

        // external suppressor test (register-cached entries, global for >16)
        u32 rm = 0;
        EXT_TEST(c0.x & 0xFFFF, 0)  EXT_TEST(c0.x >> 16, 1)
        EXT_TEST(c0.y & 0xFFFF, 2)  EXT_TEST(c0.y >> 16, 3)
        EXT_TEST(c0.z & 0xFFFF, 4)  EXT_TEST(c0.z >> 16, 5)
        EXT_TEST(c0.w & 0xFFFF, 6)  EXT_TEST(c0.w >> 16, 7)
        EXT_TEST(c1.x & 0xFFFF, 8)  EXT_TEST(c1.x >> 16, 9)
        EXT_TEST(c1.y & 0xFFFF, 10) EXT_TEST(c1.y >> 16, 11)
        EXT_TEST(c1.z & 0xFFFF, 12) EXT_TEST(c1.z >> 16, 13)
        EXT_TEST(c1.w & 0xFFFF, 14) EXT_TEST(c1.w >> 16, 15)
        for (int e = 16; e < ec; ++e) {
            int q = (int)ext[(size_t)g * ECAP + e];
            rm |= (kA[q >> 5] >> (q & 31)) & 1u;
        }
        u64 ball = __ballot(rm != 0);
        if (lane == 0) { rmw[2 * wave] = (u32)ball; rmw[2 * wave + 1] = (u32)(ball >> 32); }
        __syncthreads();

        // exact intra-chunk greedy (wave 0, rank order within chunk)
        if (wave == 0 && activeb) {
            u32 pmask = 0, chflag = 0;
            int j = lane;
#pragma unroll
            for (int u = 0; u < 4; ++u) {
                u64 tuu = ((u64)t32[((u * 4 + u) * 64 + j) * 2 + 1] << 32) | t32[((u * 4 + u) * 64 + j) * 2];
                u64 tv1 = 0, tv2 = 0, tv3 = 0;
                if (u < 3) tv1 = ((u64)t32[((u * 4 + u + 1) * 64 + j) * 2 + 1] << 32) | t32[((u * 4 + u + 1) * 64 + j) * 2];
                if (u < 2) tv2 = ((u64)t32[((u * 4 + u + 2) * 64 + j) * 2 + 1] << 32) | t32[((u * 4 + u + 2) * 64 + j) * 2];
                if (u < 1) tv3 = ((u64)t32[((u * 4 + u + 3) * 64 + j) * 2 + 1] << 32) | t32[((u * 4 + u + 3) * 64 + j) * 2];
                u32 rb = (u32)(((((u64)rmw[2 * u + 1] << 32) | rmw[2 * u]) >> j) & 1ull);
                bool alive = !rb && !((pmask >> u) & 1u) && (b * 256 + 64 * u + j < M);
                u64 ab = __ballot(alive);
                u64 kept = 0;
                while (ab) {
                    int bb = (int)__builtin_ctzll(ab);
                    kept |= 1ull << bb;
                    bool dead = (((tuu >> bb) & 1ull) != 0) || (j == bb);
                    alive = alive && !dead;
                    pmask |= ((u32)((tv1 >> bb) & 1ull)) << (u + 1);
                    pmask |= ((u32)((tv2 >> bb) & 1ull)) << (u + 2);
                    pmask |= ((u32)((tv3 >> bb) & 1ull)) << (u + 3);
                    ab = __ballot(alive);
                }
                if (j == 0) {
                    int wi = b * 8 + 2 * u;
                    u32 nlo = (u32)kept, nhi = (u32)(kept >> 32);
                    chflag |= (nlo != kA[wi]) | (nhi != kA[wi + 1]);
                    __hip_atomic_store(&B[wi], nlo, __ATOMIC_RELAXED, __HIP_MEMORY_SCOPE_AGENT);
                    __hip_atomic_store(&B[wi + 1], nhi, __ATOMIC_RELAXED, __HIP_MEMORY_SCOPE_AGENT);
                }
            }
            if (j == 0 && chflag)
                __hip_atomic_fetch_or(&changed[t], 1u, __ATOMIC_RELAXED, __HIP_MEMORY_SCOPE_AGENT);
        }
        __threadfence();
        grid.sync();
        u32 ch = __hip_atomic_load(&changed[t], __ATOMIC_RELAXED, __HIP_MEMORY_SCOPE_AGENT);
        if (ch == 0) break;          // B == A: certified fixpoint (uniform exit)
        u32* tmp = A; A = B; B = tmp;
    }

    // final values live in A (break: A==B; TMAX: A = last written after swap)
    if (tid < 8)
        keepf[b * 8 + tid] = __hip_atomic_load(&A[b * 8 + tid], __ATOMIC_RELAXED, __HIP_MEMORY_SCOPE_AGENT);
}

// ---------------------------------------------------------------------------
// K4: out[r] = sorted geometry * keep bit (exact 0/1 multiply).
// ---------------------------------------------------------------------------
__global__ void out_kernel(const float4* __restrict__ sbox, const u32* __restrict__ keepf,
                           const u16* __restrict__ gidx, const u32* __restrict__ Mptr,
                           float4* __restrict__ out, int N) {
    int r = blockIdx.x * 256 + threadIdx.x;
    if (r >= N) return;
    int M = (int)*Mptr;
    float k = 0.0f;
    if (r < M) {
        int g = (int)gidx[r];
        k = (float)((keepf[g >> 5] >> (g & 31)) & 1u);
    }
    float4 v = sbox[r];
    out[r] = make_float4(v.x * k, v.y * k, v.z * k, v.w * k);
}

// ---------------------------------------------------------------------------
extern "C" void kernel_launch(void* const* d_in, const int* in_sizes, int n_in,
                              void* d_out, int out_size, void* d_ws, size_t ws_size,
                              hipStream_t stream) {
    const float* in = (const float*)d_in[0];
    int N = in_sizes[0] / 5;          // 16384

    char* ws = (char*)d_ws;
    size_t off = 0;
    // ---- zeroed region (one memset) ----
    u32* rank    = (u32*)(ws + off); off += (size_t)N * 4;       // 64 KB
    u32* Mctr    = (u32*)(ws + off); off += 16;
    u32* changed = (u32*)(ws + off); off += (size_t)TMAX * 4;
    u32* spos    = (u32*)(ws + off); off += (size_t)N * 4;       // 64 KB
    u32* li      = (u32*)(ws + off); off += (size_t)N * 4;       // 64 KB
    u32* intraT  = (u32*)(ws + off); off += (size_t)64 * 2048 * 4; // 512 KB
    size_t zbytes = off;
    // ---- non-zeroed ----
    float4* sbox = (float4*)(ws + off); off += (size_t)N * 16;   // 256 KB
    u16* gidx    = (u16*)(ws + off);  off += (size_t)N * 2;      // 32 KB
    u16* ext     = (u16*)(ws + off);  off += (size_t)N * ECAP * 2; // 4 MB (16B-aligned)
    u16* ext_cnt = (u16*)(ws + off);  off += (size_t)N * 2;
    u32* keepA   = (u32*)(ws + off);  off += 512 * 4;
    u32* keepB   = (u32*)(ws + off);  off += 512 * 4;
    u32* keepf   = (u32*)(ws + off);  off += 512 * 4;

    hipMemsetAsync(rank, 0, zbytes, stream);

    dim3 cgrid(N / 256, N / 2048);
    rank_kernel<<<cgrid, 256, 0, stream>>>(in, rank, N);
    scatter_kernel<<<N / 256, 256, 0, stream>>>(in, rank, sbox, Mctr, N);
    spos_kernel<<<cgrid, 256, 0, stream>>>(sbox, Mctr, spos, N);
    li_kernel<<<cgrid, 256, 0, stream>>>(spos, Mctr, li, N);
    gidx_kernel<<<N / 256, 256, 0, stream>>>(spos, li, Mctr, gidx, N);

    mask_spatial_kernel<<<(N + 3) / 4, 256, 0, stream>>>(sbox, Mctr, gidx, intraT, ext, ext_cnt, N);

    void* args[] = {(void*)&intraT, (void*)&ext, (void*)&ext_cnt, (void*)&Mctr,
                    (void*)&keepA, (void*)&keepB, (void*)&changed, (void*)&keepf};
    hipLaunchCooperativeKernel((void*)nms_gs_kernel, dim3(64), dim3(256), args, 0, stream);

    out_kernel<<<N / 256, 256, 0, stream>>>(sbox, keepf, gidx, Mctr, (float4*)d_out, N);
}